// Round 8
// baseline (252.068 us; speedup 1.0000x reference)
//
#include <hip/hip_runtime.h>
#include <math.h>

// Shapes: B=3200, L=7, H=8, E=64, S=56, D=64, N=50
// queries [B,7,8,64], keys [B,56,8,64], values [B,56,8,64], mask [50,7,56]
// out [B,7,8,64] fp32.
//
// PERSISTENT WAVES, SMALL LIVE SET. R7 showed the WG-dispatch cap is real
// (~113 WG/us across R1-R6) but its 2x28-float V register arrays spilled to
// scratch at VGPR=64 (WRITE_SIZE 44.8->156 MB), poisoning the experiment.
// This version keeps the persistent 1024x256 grid (4 waves/block, 16
// waves/CU) and shrinks per-wave live state: V is consumed in 4-row groups
// with an 8-row rolling prefetch (~12 live V regs). Memory concurrency
// comes from 16 desynchronized waves/CU x ~8 loads in flight each.
// Per-unit structure otherwise as R6: K staged to a per-wave LDS slice as
// fp16 (XOR-swizzled b128 chunks, conflict-free), Q on the scalar path
// (unit index wave-uniform), softmax without max-subtraction (scores
// bounded), P transposed through the dead K slice (per-wave in-order DS
// pipe, no barriers), normalization deferred to the epilogue.

typedef __attribute__((ext_vector_type(8))) _Float16 half8;

__launch_bounds__(256, 4)
__global__ void fullattn_kernel(const float* __restrict__ q,
                                const float* __restrict__ k,
                                const float* __restrict__ v,
                                const float* __restrict__ mask,
                                float* __restrict__ out,
                                int nstations, int nunits) {
    __shared__ __align__(16) _Float16 KL4[4][56 * 64];  // 7168 B per wave slice

    const int lane = threadIdx.x & 63;
    const int wid  = __builtin_amdgcn_readfirstlane(threadIdx.x >> 6);
    _Float16* KL   = KL4[wid];
    float* pbuf    = (float*)KL;

    const int ml = (lane < 56) ? lane : 55;  // clamped s-index / K row
    const int sx = ml & 7;                   // XOR swizzle key

    const int nwaves = gridDim.x * 4;

#pragma unroll 1
    for (int u = blockIdx.x * 4 + wid; u < nunits; u += nwaves) {
        const int b  = u >> 3;
        const int h  = u & 7;
        const int st = b % nstations;

        const int kbase = b * 28672 + h * 64;  // keys/values
        const int qbase = b * 3584  + h * 64;  // queries/out

        // ---- mask rows (pre-scaled) ----
        float m[7];
#pragma unroll
        for (int l = 0; l < 7; ++l)
            m[l] = mask[st * 392 + l * 56 + ml] * 0.125f;  // scale = 1/sqrt(64)

        // ---- stage K -> LDS fp16, XOR-swizzled 16B chunks ----
        // slot f = i*64+lane: row s=f>>3, chunk c=f&7; physical chunk = c^(s&7)
#pragma unroll
        for (int i = 0; i < 7; ++i) {
            const int f = i * 64 + lane;
            const int s = f >> 3;
            const int c = f & 7;
            const float4 a0 = *(const float4*)(k + kbase + s * 512 + c * 8);
            const float4 a1 = *(const float4*)(k + kbase + s * 512 + c * 8 + 4);
            half8 hv;
            hv[0] = (_Float16)a0.x; hv[1] = (_Float16)a0.y;
            hv[2] = (_Float16)a0.z; hv[3] = (_Float16)a0.w;
            hv[4] = (_Float16)a1.x; hv[5] = (_Float16)a1.y;
            hv[6] = (_Float16)a1.z; hv[7] = (_Float16)a1.w;
            *(half8*)(&KL[s * 64 + 8 * (c ^ (s & 7))]) = hv;
        }
        // per-wave in-order DS pipe; compiler inserts lgkmcnt. No barrier:
        // each wave owns its slice; PV reads of the previous unit's P
        // precede these writes in program order.

        // ---- scores: lane = s, acc[l] = Q[l].K[s] (Q via uniform scalar loads) ----
        const float* qp = q + qbase;
        float acc[7];
#pragma unroll
        for (int l = 0; l < 7; ++l) acc[l] = 0.0f;

#pragma unroll
        for (int c = 0; c < 8; ++c) {
            const half8 kv = *(const half8*)(&KL[ml * 64 + 8 * (c ^ sx)]);
            float kf[8];
#pragma unroll
            for (int j = 0; j < 8; ++j) kf[j] = (float)kv[j];  // v_fma_mix fodder
#pragma unroll
            for (int l = 0; l < 7; ++l) {
                const float4 q0 = *(const float4*)(qp + l * 512 + c * 8);
                const float4 q1 = *(const float4*)(qp + l * 512 + c * 8 + 4);
                acc[l] = fmaf(q0.x, kf[0], acc[l]);
                acc[l] = fmaf(q0.y, kf[1], acc[l]);
                acc[l] = fmaf(q0.z, kf[2], acc[l]);
                acc[l] = fmaf(q0.w, kf[3], acc[l]);
                acc[l] = fmaf(q1.x, kf[4], acc[l]);
                acc[l] = fmaf(q1.y, kf[5], acc[l]);
                acc[l] = fmaf(q1.z, kf[6], acc[l]);
                acc[l] = fmaf(q1.w, kf[7], acc[l]);
            }
        }

        // ---- V rolling prefetch: rows 0..3 and 4..7 issued before softmax ----
        float vcur[4], vnxt[4];
#pragma unroll
        for (int i = 0; i < 4; ++i) vcur[i] = v[kbase + i * 512 + lane];
#pragma unroll
        for (int i = 0; i < 4; ++i) vnxt[i] = v[kbase + (4 + i) * 512 + lane];

        // ---- softmax across lanes (s), NO max-subtraction (scores bounded) ----
        float rdenom[7];
#pragma unroll
        for (int l = 0; l < 7; ++l) {
            const float sc = acc[l] * m[l];
            const float p  = (lane < 56) ? __expf(sc) : 0.0f;
            float sum = p;
#pragma unroll
            for (int off = 32; off >= 1; off >>= 1)
                sum += __shfl_xor(sum, off);
            pbuf[l * 64 + lane] = p;
            rdenom[l] = __builtin_amdgcn_rcpf(sum);
        }

        // ---- PV: lane = d; 4-row groups, 8-row rolling prefetch ----
        float facc[7];
#pragma unroll
        for (int l = 0; l < 7; ++l) facc[l] = 0.0f;

#pragma unroll
        for (int s4 = 0; s4 < 14; ++s4) {
            float vold[4];
#pragma unroll
            for (int i = 0; i < 4; ++i) vold[i] = vcur[i];
#pragma unroll
            for (int i = 0; i < 4; ++i) vcur[i] = vnxt[i];
            if (s4 < 12) {
#pragma unroll
                for (int i = 0; i < 4; ++i)
                    vnxt[i] = v[kbase + ((s4 + 2) * 4 + i) * 512 + lane];
            }
#pragma unroll
            for (int l = 0; l < 7; ++l) {
                const float4 p4 = *(const float4*)(&pbuf[l * 64 + s4 * 4]);  // broadcast
                facc[l] = fmaf(p4.x, vold[0], facc[l]);
                facc[l] = fmaf(p4.y, vold[1], facc[l]);
                facc[l] = fmaf(p4.z, vold[2], facc[l]);
                facc[l] = fmaf(p4.w, vold[3], facc[l]);
            }
        }

        // ---- epilogue: deferred normalization + coalesced store ----
#pragma unroll
        for (int l = 0; l < 7; ++l)
            out[qbase + l * 512 + lane] = facc[l] * rdenom[l];
    }
}

extern "C" void kernel_launch(void* const* d_in, const int* in_sizes, int n_in,
                              void* d_out, int out_size, void* d_ws, size_t ws_size,
                              hipStream_t stream) {
    const float* q    = (const float*)d_in[0];
    const float* k    = (const float*)d_in[1];
    const float* v    = (const float*)d_in[2];
    const float* mask = (const float*)d_in[3];
    float* out        = (float*)d_out;

    const int B = in_sizes[0] / (7 * 8 * 64);        // 3200
    const int nstations = in_sizes[3] / (7 * 56);    // 50
    const int nunits = B * 8;                        // 25600

    fullattn_kernel<<<dim3(1024), dim3(256), 0, stream>>>(q, k, v, mask, out,
                                                          nstations, nunits);
}

// Round 9
// 215.347 us; speedup vs baseline: 1.1705x; 1.1705x over previous
//
#include <hip/hip_runtime.h>
#include <math.h>

// Shapes: B=3200, L=7, H=8, E=64, S=56, D=64, N=50
// queries [B,7,8,64], keys [B,56,8,64], values [B,56,8,64], mask [50,7,56]
// out [B,7,8,64] fp32.
//
// CONTIGUOUS-STREAM BLOCKS. R1-R8 all loaded K/V as 256B-per-instruction at
// 2KB stride (one head's slice) -> DRAM page efficiency capped delivered BW
// at ~2 TB/s regardless of occupancy (27-54%) or persistence. This version
// assigns one 512-thread block per batch b and streams K[b] (114 KB) and
// V[b] (114 KB) FULLY CONTIGUOUSLY (1 KB sequential per wave-instruction)
// into a shared fp16 LDS buffer, computing all 8 heads inside the block.
//   phase 1: stage K[b] -> LDS fp16 (XOR-swizzled 16B chunks per (s,h) row
//            for conflict-free score reads); prefetch V[b] rows 0..31 into
//            registers (keeps HBM streaming during scores).
//   phase 2: per-wave (wave = head): scores via scalar-path Q, shuffle
//            softmax (no max-subtraction; scores bounded), P -> LDS fp16.
//   phase 3: stage V[b] -> same LDS buffer, LINEAR layout (PV reads are
//            conflict-free without swizzle: lane=d reads 128B rows).
//   phase 4: PV from LDS + deferred normalization, coalesced store.
// LDS = 57344 (K/V) + 7168 (P) = 64512 B -> 2 blocks/CU = 16 waves/CU.

typedef __attribute__((ext_vector_type(8))) _Float16 half8;

static __device__ __forceinline__ half8 cvt8(const float4 a, const float4 b) {
    half8 h;
    h[0] = (_Float16)a.x; h[1] = (_Float16)a.y;
    h[2] = (_Float16)a.z; h[3] = (_Float16)a.w;
    h[4] = (_Float16)b.x; h[5] = (_Float16)b.y;
    h[6] = (_Float16)b.z; h[7] = (_Float16)b.w;
    return h;
}

__launch_bounds__(512, 4)
__global__ void fullattn_kernel(const float* __restrict__ q,
                                const float* __restrict__ k,
                                const float* __restrict__ v,
                                const float* __restrict__ mask,
                                float* __restrict__ out,
                                int nstations) {
    __shared__ __align__(16) _Float16 KV[28672];      // 57344 B: K, then V (reused)
    __shared__ __align__(16) _Float16 P[8 * 7 * 64];  // 7168 B, rows padded to 64

    const int t    = threadIdx.x;
    const int lane = t & 63;
    const int w    = __builtin_amdgcn_readfirstlane(t >> 6);  // wave id = head h
    const int b    = blockIdx.x;
    const int st   = b % nstations;

    const int kb = b * 28672;   // k/v float base of batch b
    const int qb = b * 3584;    // q/out float base of batch b

    // ---------- phase 1: stage K[b] contiguously; prefetch V[0:32) ----------
    // thread t, iter i covers global floats g = i*4096 + t*8 (8 consecutive).
    // decode: s = i*8 + w (wave-uniform), hh = (lane>>3), c = t&7.
    // K phys half-index: s*512 + hh*64 + ((c ^ (s&7))<<3)  (chunk XOR swizzle)
    {
        const float* kp = k + kb + t * 8;
        const int hh = lane >> 3;
        const int c  = t & 7;
#pragma unroll
        for (int i = 0; i < 7; ++i) {
            const float4 a0 = *(const float4*)(kp + i * 4096);
            const float4 a1 = *(const float4*)(kp + i * 4096 + 4);
            const int s = i * 8 + w;
            *(half8*)(&KV[s * 512 + hh * 64 + ((c ^ (s & 7)) << 3)]) = cvt8(a0, a1);
        }
    }
    // V prefetch rows 0..31 (first 16384 floats) into registers
    float4 vp[8];
    {
        const float* vpg = v + kb + t * 8;
#pragma unroll
        for (int i = 0; i < 4; ++i) {
            vp[2 * i]     = *(const float4*)(vpg + i * 4096);
            vp[2 * i + 1] = *(const float4*)(vpg + i * 4096 + 4);
        }
    }
    __syncthreads();  // K fully staged

    // ---------- phase 2: scores + softmax (wave = head w) ----------
    const int ml  = (lane < 56) ? lane : 55;  // clamped s index
    const int sxr = ml & 7;

    float m[7];
#pragma unroll
    for (int l = 0; l < 7; ++l)
        m[l] = mask[st * 392 + l * 56 + ml] * 0.125f;  // scale = 1/sqrt(64)

    const float* qp = q + qb + w * 64;  // wave-uniform -> scalar path
    float acc[7];
#pragma unroll
    for (int l = 0; l < 7; ++l) acc[l] = 0.0f;

#pragma unroll
    for (int c = 0; c < 8; ++c) {
        const half8 kv8 = *(const half8*)(&KV[ml * 512 + w * 64 + ((c ^ sxr) << 3)]);
        float kf[8];
#pragma unroll
        for (int j = 0; j < 8; ++j) kf[j] = (float)kv8[j];
#pragma unroll
        for (int l = 0; l < 7; ++l) {
            const float4 q0 = *(const float4*)(qp + l * 512 + c * 8);
            const float4 q1 = *(const float4*)(qp + l * 512 + c * 8 + 4);
            acc[l] = fmaf(q0.x, kf[0], acc[l]);
            acc[l] = fmaf(q0.y, kf[1], acc[l]);
            acc[l] = fmaf(q0.z, kf[2], acc[l]);
            acc[l] = fmaf(q0.w, kf[3], acc[l]);
            acc[l] = fmaf(q1.x, kf[4], acc[l]);
            acc[l] = fmaf(q1.y, kf[5], acc[l]);
            acc[l] = fmaf(q1.z, kf[6], acc[l]);
            acc[l] = fmaf(q1.w, kf[7], acc[l]);
        }
    }

    // softmax across lanes (s); no max-subtraction (|score*0.125| bounded);
    // all 64 lanes write their own P slot (pad lanes write 0, never read).
    float rdenom[7];
#pragma unroll
    for (int l = 0; l < 7; ++l) {
        const float sc = acc[l] * m[l];
        const float p  = (lane < 56) ? __expf(sc) : 0.0f;
        float sum = p;
#pragma unroll
        for (int off = 32; off >= 1; off >>= 1)
            sum += __shfl_xor(sum, off);
        P[w * 448 + l * 64 + lane] = (_Float16)p;
        rdenom[l] = __builtin_amdgcn_rcpf(sum);
    }
    __syncthreads();  // everyone done reading K + writing P

    // ---------- phase 3: stage V[b] into KV, LINEAR layout ----------
    {
#pragma unroll
        for (int i = 0; i < 4; ++i)
            *(half8*)(&KV[i * 4096 + t * 8]) = cvt8(vp[2 * i], vp[2 * i + 1]);
        const float* vpg = v + kb + t * 8;
#pragma unroll
        for (int i = 4; i < 7; ++i) {
            const float4 a0 = *(const float4*)(vpg + i * 4096);
            const float4 a1 = *(const float4*)(vpg + i * 4096 + 4);
            *(half8*)(&KV[i * 4096 + t * 8]) = cvt8(a0, a1);
        }
    }
    __syncthreads();  // V fully staged

    // ---------- phase 4: PV (lane = d) + epilogue ----------
    float facc[7];
#pragma unroll
    for (int l = 0; l < 7; ++l) facc[l] = 0.0f;

    const int vbase = w * 64 + lane;  // element d of head w
#pragma unroll
    for (int sc8 = 0; sc8 < 7; ++sc8) {
        float vv[8];
#pragma unroll
        for (int j = 0; j < 8; ++j)
            vv[j] = (float)KV[(sc8 * 8 + j) * 512 + vbase];
#pragma unroll
        for (int l = 0; l < 7; ++l) {
            const half8 p8 = *(const half8*)(&P[w * 448 + l * 64 + sc8 * 8]);  // uniform bcast
            facc[l] = fmaf((float)p8[0], vv[0], facc[l]);
            facc[l] = fmaf((float)p8[1], vv[1], facc[l]);
            facc[l] = fmaf((float)p8[2], vv[2], facc[l]);
            facc[l] = fmaf((float)p8[3], vv[3], facc[l]);
            facc[l] = fmaf((float)p8[4], vv[4], facc[l]);
            facc[l] = fmaf((float)p8[5], vv[5], facc[l]);
            facc[l] = fmaf((float)p8[6], vv[6], facc[l]);
            facc[l] = fmaf((float)p8[7], vv[7], facc[l]);
        }
    }

#pragma unroll
    for (int l = 0; l < 7; ++l)
        out[qb + l * 512 + vbase] = facc[l] * rdenom[l];
}

extern "C" void kernel_launch(void* const* d_in, const int* in_sizes, int n_in,
                              void* d_out, int out_size, void* d_ws, size_t ws_size,
                              hipStream_t stream) {
    const float* q    = (const float*)d_in[0];
    const float* k    = (const float*)d_in[1];
    const float* v    = (const float*)d_in[2];
    const float* mask = (const float*)d_in[3];
    float* out        = (float*)d_out;

    const int B = in_sizes[0] / (7 * 8 * 64);        // 3200
    const int nstations = in_sizes[3] / (7 * 56);    // 50

    fullattn_kernel<<<dim3(B), dim3(512), 0, stream>>>(q, k, v, mask, out, nstations);
}